// Round 2
// baseline (390.505 us; speedup 1.0000x reference)
//
#include <hip/hip_runtime.h>
#include <hip/hip_bf16.h>

// Problem constants (from reference)
#define Jd   128   // feature dim
#define Cn   512   // num classes
#define TLn  16    // label seq length
#define Bn   32    // batch
#define T0n  2048

// ---------------------------------------------------------------------------
// Reduction of the reference (x and lens are dead inputs; batch-uniform):
//   pred0   = sos @ W                                   [J]
//   s_0     = argmin_c ||pred0 - L[c,0]||^2 / J
//   P_t     = L[s_{t-1}] @ W                            [TL,J]  (only rows < t used)
//   s_t     = argmin_c (1/(J*t)) sum_{tau<t} ||P_t[tau] - L[c,tau]||^2
//   out     = concat( broadcast_B(s_16), broadcast_B(L[s_15] @ W) )   (f32)
// Ties: jnp.argmin takes first index -> packed (simbits<<32 | c) atomicMin.
// Workspace: only 17 x u64 argmin keys (immune to ws_size).
// ---------------------------------------------------------------------------

__global__ void k_keys(unsigned long long* __restrict__ key) {
    int j = threadIdx.x;
    if (j <= TLn) key[j] = 0xFFFFFFFFFFFFFFFFull;
}

// grid = Cn blocks x Jd threads; one launch per t = 0..16 (stream-ordered dep).
__global__ void k_iter(const float* __restrict__ sos,
                       const float* __restrict__ L,
                       const float* __restrict__ W,
                       unsigned long long* __restrict__ key,
                       int t) {
    int c = blockIdx.x;
    int j = threadIdx.x;
    float partial = 0.f;

    if (t == 0) {
        // pred0[j] = sos . W[:,j]; compare against L[c,0,:]
        __shared__ float srow[Jd];
        srow[j] = sos[j];
        __syncthreads();
        float acc = 0.f;
        #pragma unroll 8
        for (int k = 0; k < Jd; ++k) acc = fmaf(srow[k], W[k * Jd + j], acc);
        float d = acc - L[c * TLn * Jd + j];
        partial = d * d;
    } else {
        int s = (int)(key[t - 1] & 0xFFFFFFFFull);   // uniform across block
        __shared__ float Ls[TLn * Jd];               // 8 KB: rows of L[s]
        for (int idx = j; idx < TLn * Jd; idx += Jd)
            Ls[idx] = (idx < t * Jd) ? L[s * TLn * Jd + idx] : 0.f;
        __syncthreads();

        // p[tau] = L[s,tau,:] . W[:,j]  — fixed-bound unrolled so p stays in VGPRs
        float p[TLn];
        #pragma unroll
        for (int tau = 0; tau < TLn; ++tau) p[tau] = 0.f;
        for (int k = 0; k < Jd; ++k) {
            float w = W[k * Jd + j];                 // coalesced, L2-broadcast
            #pragma unroll
            for (int tau = 0; tau < TLn; ++tau)
                p[tau] = fmaf(Ls[tau * Jd + k], w, p[tau]);  // LDS broadcast read
        }
        #pragma unroll
        for (int tau = 0; tau < TLn; ++tau) {
            if (tau < t) {
                float d = p[tau] - L[(c * TLn + tau) * Jd + j];
                partial = fmaf(d, d, partial);
            }
        }
    }

    // block reduction over 128 threads (2 waves)
    for (int o = 32; o > 0; o >>= 1) partial += __shfl_down(partial, o, 64);
    __shared__ float tmp[2];
    if ((j & 63) == 0) tmp[j >> 6] = partial;
    __syncthreads();
    if (j == 0) {
        float sim = (tmp[0] + tmp[1]) / (float)(Jd * (t == 0 ? 1 : t));
        // sim >= 0 -> f32 bits order like the float; low bits carry c
        unsigned long long kk =
            ((unsigned long long)__float_as_uint(sim) << 32) | (unsigned int)c;
        atomicMin(&key[t], kk);
    }
}

// grid = Bn*TLn blocks x Jd threads: out = [sofar(32) | pls(B,TL,J)] as f32
__global__ void k_out(const float* __restrict__ L,
                      const float* __restrict__ W,
                      const unsigned long long* __restrict__ key,
                      float* __restrict__ out) {
    int bt = blockIdx.x;              // b*TLn + tau
    int tau = bt & (TLn - 1);
    int j = threadIdx.x;
    int s_final = (int)(key[TLn] & 0xFFFFFFFFull);
    int s_prev  = (int)(key[TLn - 1] & 0xFFFFFFFFull);

    __shared__ float Lrow[Jd];
    Lrow[j] = L[(s_prev * TLn + tau) * Jd + j];
    __syncthreads();
    float acc = 0.f;
    #pragma unroll 8
    for (int k = 0; k < Jd; ++k) acc = fmaf(Lrow[k], W[k * Jd + j], acc);

    out[Bn + bt * Jd + j] = acc;      // pls, identical for every batch row
    if (bt == 0 && j < Bn) out[j] = (float)s_final;
}

extern "C" void kernel_launch(void* const* d_in, const int* in_sizes, int n_in,
                              void* d_out, int out_size, void* d_ws, size_t ws_size,
                              hipStream_t stream) {
    // inputs: 0:x (unused f32), 1:lens (unused i32), 2:sos f32, 3:label_seqs f32, 4:W f32
    const float* sos = (const float*)d_in[2];
    const float* L   = (const float*)d_in[3];
    const float* W   = (const float*)d_in[4];
    float* out = (float*)d_out;

    unsigned long long* key = (unsigned long long*)d_ws;   // 17 * 8 B

    hipLaunchKernelGGL(k_keys, dim3(1), dim3(32), 0, stream, key);
    for (int t = 0; t <= TLn; ++t)
        hipLaunchKernelGGL(k_iter, dim3(Cn), dim3(Jd), 0, stream, sos, L, W, key, t);
    hipLaunchKernelGGL(k_out, dim3(Bn * TLn), dim3(Jd), 0, stream, L, W, key, out);
}